// Round 11
// baseline (59.643 us; speedup 1.0000x reference)
//
#include <hip/hip_runtime.h>
#include <hip/hip_bf16.h>

#define MASK_ID 50264
#define Bn 16
#define Sn 2048
#define Hn 1024
#define Ln 128

typedef __attribute__((ext_vector_type(8))) short short8;
typedef __attribute__((ext_vector_type(4))) float f32x4;

__device__ __forceinline__ unsigned short f2bf(float f) {
    __hip_bfloat16 h = __float2bfloat16(f);
    return __builtin_bit_cast(unsigned short, h);
}
__device__ __forceinline__ short8 cvt8(float4 lo, float4 hi) {
    short8 r;
    r[0] = (short)f2bf(lo.x); r[1] = (short)f2bf(lo.y);
    r[2] = (short)f2bf(lo.z); r[3] = (short)f2bf(lo.w);
    r[4] = (short)f2bf(hi.x); r[5] = (short)f2bf(hi.y);
    r[6] = (short)f2bf(hi.z); r[7] = (short)f2bf(hi.w);
    return r;
}

// ======== K1: fused gather + f32->bf16 + barrier-free MFMA GEMM ========
// 256 blocks (16 by x 16 bx, XCD-partitioned), 4 waves; wave = 32 rows x 64 cols.
// K-loop reads seq/W f32 straight from global (L2), converts in regs, MFMAs.
// No LDS and no __syncthreads in the K-loop; register double-buffer (named sets).
struct Frag {
    float4 a0l, a0h, a1l, a1h;
    float4 b0l, b0h, b1l, b1h, b2l, b2h, b3l, b3h;
};

__global__ __launch_bounds__(256, 2) void gemm11_k(
        const int* __restrict__ ids, const float* __restrict__ q,
        const float* __restrict__ seq, const int* __restrict__ offsets,
        const float* __restrict__ W, const float* __restrict__ bias,
        float* __restrict__ yn2p, float* __restrict__ dotp, float* __restrict__ xn2p)
{
    __shared__ int   offs[128];
    __shared__ int   t4[4];
    __shared__ unsigned short qs[1024];      // q row bf16, linear
    __shared__ float xvs[64];
    __shared__ float xred[4];
    __shared__ float red[128][2];

    const int blk = blockIdx.x, tid = threadIdx.x;
    const int wv = tid >> 6, l = tid & 63;
    // XCD partition: XCD x gets 4 by x 8 bx (~4MB working set per XCD)
    const int x = blk & 7, ib = blk >> 3;
    const int by = (x >> 1) * 4 + (ib >> 3);
    const int bx = (x & 1) * 8 + (ib & 7);
    const int rbase = by * 128, cbase = bx * 64;
    const int l15 = l & 15, kgrp = l >> 4;

    if (tid < 128) offs[tid] = offsets[tid];

    // ---- maskpos for this block's batch ----
    int lm = Sn;
    const int* idrow = ids + by * Sn;
    for (int s = tid; s < Sn; s += 256)
        if (idrow[s] == MASK_ID) lm = min(lm, s);
    #pragma unroll
    for (int m = 32; m; m >>= 1) lm = min(lm, __shfl_xor(lm, m));
    if (l == 0) t4[wv] = lm;
    __syncthreads();                          // covers offs[] and t4[]
    int mp = min(min(t4[0], t4[1]), min(t4[2], t4[3]));
    if (mp == Sn) mp = 0;

    // ---- q row -> bf16 LDS ----
    {
        float4 v = ((const float4*)(q + ((size_t)by * Sn + mp) * Hn))[tid];
        ((ushort4*)qs)[tid] = make_ushort4(f2bf(v.x), f2bf(v.y), f2bf(v.z), f2bf(v.w));
    }

    // ---- per-lane fragment row pointers (f32, +kgrp*8 element offset) ----
    const int lrow0 = wv * 32 + l15;
    const int lrow1 = lrow0 + 16;
    const float* aR0 = seq + ((size_t)by * Sn + (size_t)offs[lrow0]) * Hn + kgrp * 8;
    const float* aR1 = seq + ((size_t)by * Sn + (size_t)offs[lrow1]) * Hn + kgrp * 8;
    const float* bR0 = W + (size_t)(cbase +  0 + l15) * Hn + kgrp * 8;
    const float* bR1 = W + (size_t)(cbase + 16 + l15) * Hn + kgrp * 8;
    const float* bR2 = W + (size_t)(cbase + 32 + l15) * Hn + kgrp * 8;
    const float* bR3 = W + (size_t)(cbase + 48 + l15) * Hn + kgrp * 8;
    const char* qsB = (const char*)qs;
    __syncthreads();                          // qs ready; last barrier before K-loop

    f32x4 acc[2][4];
    #pragma unroll
    for (int i = 0; i < 2; ++i)
        #pragma unroll
        for (int j = 0; j < 4; ++j) acc[i][j] = (f32x4){0.f, 0.f, 0.f, 0.f};
    f32x4 xacc = {0.f, 0.f, 0.f, 0.f};

    #define LOADF(F, ks_) do { \
        (F).a0l = *(const float4*)(aR0 + (ks_) * 32); (F).a0h = *(const float4*)(aR0 + (ks_) * 32 + 4); \
        (F).a1l = *(const float4*)(aR1 + (ks_) * 32); (F).a1h = *(const float4*)(aR1 + (ks_) * 32 + 4); \
        (F).b0l = *(const float4*)(bR0 + (ks_) * 32); (F).b0h = *(const float4*)(bR0 + (ks_) * 32 + 4); \
        (F).b1l = *(const float4*)(bR1 + (ks_) * 32); (F).b1h = *(const float4*)(bR1 + (ks_) * 32 + 4); \
        (F).b2l = *(const float4*)(bR2 + (ks_) * 32); (F).b2h = *(const float4*)(bR2 + (ks_) * 32 + 4); \
        (F).b3l = *(const float4*)(bR3 + (ks_) * 32); (F).b3h = *(const float4*)(bR3 + (ks_) * 32 + 4); \
    } while (0)

    #define COMPUTE(F, ks_) do { \
        short8 a0 = cvt8((F).a0l, (F).a0h); \
        short8 a1 = cvt8((F).a1l, (F).a1h); \
        short8 b0 = cvt8((F).b0l, (F).b0h); \
        short8 b1 = cvt8((F).b1l, (F).b1h); \
        short8 b2 = cvt8((F).b2l, (F).b2h); \
        short8 b3 = cvt8((F).b3l, (F).b3h); \
        short8 aq = *(const short8*)(qsB + (ks_) * 64 + kgrp * 16); \
        acc[0][0] = __builtin_amdgcn_mfma_f32_16x16x32_bf16(a0, b0, acc[0][0], 0, 0, 0); \
        acc[0][1] = __builtin_amdgcn_mfma_f32_16x16x32_bf16(a0, b1, acc[0][1], 0, 0, 0); \
        acc[0][2] = __builtin_amdgcn_mfma_f32_16x16x32_bf16(a0, b2, acc[0][2], 0, 0, 0); \
        acc[0][3] = __builtin_amdgcn_mfma_f32_16x16x32_bf16(a0, b3, acc[0][3], 0, 0, 0); \
        acc[1][0] = __builtin_amdgcn_mfma_f32_16x16x32_bf16(a1, b0, acc[1][0], 0, 0, 0); \
        acc[1][1] = __builtin_amdgcn_mfma_f32_16x16x32_bf16(a1, b1, acc[1][1], 0, 0, 0); \
        acc[1][2] = __builtin_amdgcn_mfma_f32_16x16x32_bf16(a1, b2, acc[1][2], 0, 0, 0); \
        acc[1][3] = __builtin_amdgcn_mfma_f32_16x16x32_bf16(a1, b3, acc[1][3], 0, 0, 0); \
        short8 bw = (wv == 0) ? b0 : (wv == 1) ? b1 : (wv == 2) ? b2 : b3; \
        xacc = __builtin_amdgcn_mfma_f32_16x16x32_bf16(aq, bw, xacc, 0, 0, 0); \
    } while (0)

    Frag fA, fB;
    LOADF(fA, 0);
    for (int ks = 0; ks < 32; ks += 2) {
        LOADF(fB, ks + 1);                  // load-ahead hides under COMPUTE(fA)
        COMPUTE(fA, ks);
        if (ks + 2 < 32) LOADF(fA, ks + 2); // load-ahead hides under COMPUTE(fB)
        COMPUTE(fB, ks + 1);
    }
    #undef LOADF
    #undef COMPUTE

    // ---- x publish: wave wv owns cols [wv*16, wv*16+16) ----
    float bvx = bias[cbase + wv * 16 + l15];
    float xv_own = xacc[0] + bvx;            // all D rows identical; reg0 ok
    if (l < 16) xvs[wv * 16 + l] = xv_own;
    {
        float px = (l < 16) ? xv_own * xv_own : 0.f;
        #pragma unroll
        for (int m = 1; m < 16; m <<= 1) px += __shfl_xor(px, m);
        if (l == 0) xred[wv] = px;
    }
    __syncthreads();

    // ---- per-row partials over this block's 64 cols ----
    float xv[4], bv[4];
    #pragma unroll
    for (int nf = 0; nf < 4; ++nf) {
        xv[nf] = xvs[nf * 16 + l15];
        bv[nf] = bias[cbase + nf * 16 + l15];
    }
    #pragma unroll
    for (int i = 0; i < 2; ++i) {
        #pragma unroll
        for (int reg = 0; reg < 4; ++reg) {
            float y2v = 0.f, xyv = 0.f;
            #pragma unroll
            for (int nf = 0; nf < 4; ++nf) {
                float y = acc[i][nf][reg] + bv[nf];
                y2v += y * y;
                xyv += xv[nf] * y;
            }
            #pragma unroll
            for (int m = 1; m < 16; m <<= 1) {
                y2v += __shfl_xor(y2v, m);
                xyv += __shfl_xor(xyv, m);
            }
            if (l15 == 0) {
                int lrow = wv * 32 + i * 16 + (l >> 4) * 4 + reg;
                red[lrow][0] = y2v;
                red[lrow][1] = xyv;
            }
        }
    }
    __syncthreads();
    if (tid < 128) yn2p[(size_t)(rbase + tid) * 16 + bx] = red[tid][0];
    else           dotp[(size_t)(rbase + tid - 128) * 16 + bx] = red[tid - 128][1];
    if (tid == 0)  xn2p[by * 16 + bx] = xred[0] + xred[1] + xred[2] + xred[3];
}

// ======== K2: finalize (plain vectorized loads; kernel boundary = coherence) ====
__global__ __launch_bounds__(1024) void final11_k(
        const float* __restrict__ yn2p, const float* __restrict__ dotp,
        const float* __restrict__ xn2p,
        const int* __restrict__ labels, const int* __restrict__ events,
        float* __restrict__ out)
{
    __shared__ float xns[16], wn[32], wd[32], ln16[16];
    const int tid = threadIdx.x;
    const int w = tid >> 6, l = tid & 63;

    if (tid < 16) {
        const f32x4* p = (const f32x4*)(xn2p + tid * 16);
        f32x4 s4 = p[0] + p[1] + p[2] + p[3];
        xns[tid] = sqrtf(s4[0] + s4[1] + s4[2] + s4[3]);
    }
    __syncthreads();

    #pragma unroll
    for (int h = 0; h < 2; ++h) {
        int row = h * 1024 + tid;
        const f32x4* py = (const f32x4*)(yn2p + (size_t)row * 16);
        const f32x4* pd = (const f32x4*)(dotp + (size_t)row * 16);
        f32x4 sy = py[0] + py[1] + py[2] + py[3];
        f32x4 sd = pd[0] + pd[1] + pd[2] + pd[3];
        float y2 = sy[0] + sy[1] + sy[2] + sy[3];
        float dt = sd[0] + sd[1] + sd[2] + sd[3];
        int b = row >> 7;                        // uniform per wave
        float c = dt / fmaxf(xns[b] * sqrtf(y2), 1e-8f);
        float e = expf(c);
        float numt = e * (float)labels[row];
        float dent = e * (float)events[row];
        #pragma unroll
        for (int m = 32; m; m >>= 1) { numt += __shfl_xor(numt, m); dent += __shfl_xor(dent, m); }
        if (l == 0) { wn[h * 16 + w] = numt; wd[h * 16 + w] = dent; }
    }
    __syncthreads();
    if (tid < 16) {
        int s0 = (tid >> 3) * 16 + (tid & 7) * 2;
        float num = wn[s0] + wn[s0 + 1];
        float den = wd[s0] + wd[s0 + 1];
        ln16[tid] = logf(den) - logf(num);
    }
    __syncthreads();
    if (w == 0) {
        float v = (l < 16) ? ln16[l] : 0.f;
        #pragma unroll
        for (int m = 32; m; m >>= 1) v += __shfl_xor(v, m);
        if (l == 0) out[0] = v * (1.0f / Bn);
    }
}

extern "C" void kernel_launch(void* const* d_in, const int* in_sizes, int n_in,
                              void* d_out, int out_size, void* d_ws, size_t ws_size,
                              hipStream_t stream) {
    const int*   input_ids = (const int*)d_in[0];
    const float* q         = (const float*)d_in[1];
    const float* seq       = (const float*)d_in[2];
    const int*   events    = (const int*)d_in[3];
    const int*   labels    = (const int*)d_in[4];
    const int*   offsets   = (const int*)d_in[5];
    const float* W         = (const float*)d_in[7];
    const float* bias      = (const float*)d_in[8];
    float* out = (float*)d_out;

    char* ws = (char*)d_ws;
    float* yn2p = (float*)(ws);              // 128 KB [2048][16]
    float* dotp = (float*)(ws + 131072);     // 128 KB [2048][16]
    float* xn2p = (float*)(ws + 262144);     //   1 KB [16][16]

    gemm11_k<<<256, 256, 0, stream>>>(input_ids, q, seq, offsets, W, bias,
                                      yn2p, dotp, xn2p);
    final11_k<<<1, 1024, 0, stream>>>(yn2p, dotp, xn2p, labels, events, out);
}